// Round 1
// baseline (251.593 us; speedup 1.0000x reference)
//
#include <hip/hip_runtime.h>
#include <hip/hip_bf16.h>

// Black-Scholes "all" pricing: out[i] = (call, put, digital_call, digital_put)
// Inputs: S0, K, T, vt  (float32, N each).  Output: float32 [N,4].
// Memory-bound elementwise op: 32 B/option traffic -> target ~43 us at 6.3 TB/s.

#define BS_R 0.02f
#define BS_Q 0.01f

__device__ __forceinline__ void bs_one(float s, float k, float t, float v,
                                       float4& o) {
    const float inv_sqrt2 = 0.7071067811865476f;
    float sv = sqrtf(v * t);
    float d1 = (logf(s / k) + (BS_R - BS_Q + v * 0.5f) * t) / sv;
    float d2 = d1 - sv;
    float N1 = 0.5f * (1.0f + erff(d1 * inv_sqrt2));
    float N2 = 0.5f * (1.0f + erff(d2 * inv_sqrt2));
    float disc_r = expf(-BS_R * t);
    float disc_q = expf(-BS_Q * t);
    float call = s * disc_q * N1 - k * disc_r * N2;
    float put  = -s * disc_q * (1.0f - N1) + k * disc_r * (1.0f - N2);
    float dc = disc_r * N2;
    float dp = disc_r * (1.0f - N2);
    // expired (t == 0) branch: intrinsic / indicator payoffs (predicated)
    bool expired = (t == 0.0f);
    if (expired) {
        call = fmaxf(s - k, 0.0f);
        put  = fmaxf(k - s, 0.0f);
        dc   = (s > k) ? 1.0f : 0.0f;
        dp   = (s <= k) ? 1.0f : 0.0f;
    }
    o.x = call; o.y = put; o.z = dc; o.w = dp;
}

__global__ void __launch_bounds__(256)
bs_all_kernel(const float4* __restrict__ S0, const float4* __restrict__ K,
              const float4* __restrict__ T, const float4* __restrict__ vt,
              float4* __restrict__ out, int n4) {
    int stride = gridDim.x * blockDim.x;
    for (int i = blockIdx.x * blockDim.x + threadIdx.x; i < n4; i += stride) {
        float4 s = S0[i];
        float4 k = K[i];
        float4 t = T[i];
        float4 v = vt[i];
        float4 o0, o1, o2, o3;
        bs_one(s.x, k.x, t.x, v.x, o0);
        bs_one(s.y, k.y, t.y, v.y, o1);
        bs_one(s.z, k.z, t.z, v.z, o2);
        bs_one(s.w, k.w, t.w, v.w, o3);
        // one option == one float4 of output -> 4 contiguous float4 stores
        float4* op = out + (size_t)i * 4;
        op[0] = o0; op[1] = o1; op[2] = o2; op[3] = o3;
    }
}

extern "C" void kernel_launch(void* const* d_in, const int* in_sizes, int n_in,
                              void* d_out, int out_size, void* d_ws, size_t ws_size,
                              hipStream_t stream) {
    const float* S0 = (const float*)d_in[0];
    const float* K  = (const float*)d_in[1];
    const float* T  = (const float*)d_in[2];
    const float* vt = (const float*)d_in[3];
    float* out = (float*)d_out;
    int n = in_sizes[0];
    int n4 = n / 4;  // N = 8388608 divisible by 4

    int block = 256;
    int grid = (n4 + block - 1) / block;
    if (grid > 2048) grid = 2048;  // grid-stride, ~8 blocks/CU
    bs_all_kernel<<<grid, block, 0, stream>>>(
        (const float4*)S0, (const float4*)K, (const float4*)T, (const float4*)vt,
        (float4*)out, n4);
}

// Round 2
// 242.916 us; speedup vs baseline: 1.0357x; 1.0357x over previous
//
#include <hip/hip_runtime.h>
#include <hip/hip_bf16.h>

// Black-Scholes "all" pricing: out[i] = (call, put, digital_call, digital_put)
// Inputs: S0, K, T, vt (float32, N each). Output: float32 [N,4].
// Memory-bound elementwise op: ~32 B/option HBM traffic -> target ~35 us.
//
// Fast-math formulation (threshold is 0.985 absolute; errors below ~0.05):
//   log(S/K)   = (log2(S) - log2(K)) * ln2          (2x v_log_f32, no divide)
//   1/sv, sv   = rsq(v*t), (v*t)*rsq(v*t)           (1x v_rsq_f32, no sqrt/div)
//   exp(c*t)   = exp2(c*log2e*t)                    (v_exp_f32)
//   Phi(d)     = 1/(1+exp2(a*d + b*d^3))            (Page 1977 logistic,
//                a=-1.5976*log2e, b=-0.070566*log2e; |err| <= 1.4e-4;
//                saturates correctly for |d|>6: exp2->{0,inf}, rcp(inf)=0)
//   put        = call - S*disc_q + K*disc_r         (put-call parity, exact)

__global__ void __launch_bounds__(256)
bs_all_kernel(const float* __restrict__ S0, const float* __restrict__ K,
              const float* __restrict__ T, const float* __restrict__ vt,
              float4* __restrict__ out, int n) {
    const float LN2 = 0.69314718055994531f;
    const float A   = -2.3048706f;    // -1.5976   * log2(e)
    const float B   = -0.10180522f;   // -0.070566 * log2(e)
    const float CR  = -0.028853901f;  // -0.02 * log2(e)
    const float CQ  = -0.014426951f;  // -0.01 * log2(e)

    int stride = gridDim.x * blockDim.x;
    for (int i = blockIdx.x * blockDim.x + threadIdx.x; i < n; i += stride) {
        float s = S0[i];
        float k = K[i];
        float t = T[i];
        float v = vt[i];

        float x      = v * t;
        float inv_sv = __builtin_amdgcn_rsqf(x);   // 1/sqrt(v*t)
        float sv     = x * inv_sv;                 // sqrt(v*t)

        float lg = (__builtin_amdgcn_logf(s) - __builtin_amdgcn_logf(k)) * LN2;
        float d1 = (lg + fmaf(0.5f, v, 0.01f) * t) * inv_sv;  // R-Q = 0.01
        float d2 = d1 - sv;

        // Phi(d) = 1/(1 + exp2(d*(A + B*d^2)))
        float a1 = d1 * fmaf(B, d1 * d1, A);
        float a2 = d2 * fmaf(B, d2 * d2, A);
        float N1 = __builtin_amdgcn_rcpf(1.0f + __builtin_amdgcn_exp2f(a1));
        float N2 = __builtin_amdgcn_rcpf(1.0f + __builtin_amdgcn_exp2f(a2));

        float disc_r = __builtin_amdgcn_exp2f(CR * t);
        float disc_q = __builtin_amdgcn_exp2f(CQ * t);

        float sq = s * disc_q;
        float kr = k * disc_r;
        float call = fmaf(sq, N1, -kr * N2);
        float put  = call - sq + kr;             // put-call parity
        float dc   = disc_r * N2;
        float dp   = disc_r - dc;                // disc_r * (1 - N2)

        // expired (t == 0): intrinsic / indicator payoffs (predicated; also
        // cleans up the NaNs from rsq(0) above)
        bool e = (t == 0.0f);
        call = e ? fmaxf(s - k, 0.0f) : call;
        put  = e ? fmaxf(k - s, 0.0f) : put;
        dc   = e ? ((s > k)  ? 1.0f : 0.0f) : dc;
        dp   = e ? ((s <= k) ? 1.0f : 0.0f) : dp;

        out[i] = make_float4(call, put, dc, dp);  // coalesced 16 B/lane store
    }
}

extern "C" void kernel_launch(void* const* d_in, const int* in_sizes, int n_in,
                              void* d_out, int out_size, void* d_ws, size_t ws_size,
                              hipStream_t stream) {
    const float* S0 = (const float*)d_in[0];
    const float* K  = (const float*)d_in[1];
    const float* T  = (const float*)d_in[2];
    const float* vt = (const float*)d_in[3];
    float* out = (float*)d_out;
    int n = in_sizes[0];

    int block = 256;
    int grid = 2048;  // grid-stride; ~8 blocks/CU on 256 CUs
    bs_all_kernel<<<grid, block, 0, stream>>>(S0, K, T, vt, (float4*)out, n);
}

// Round 8
// 231.457 us; speedup vs baseline: 1.0870x; 1.0495x over previous
//
#include <hip/hip_runtime.h>
#include <hip/hip_bf16.h>

// Black-Scholes "all" pricing: out[i] = (call, put, digital_call, digital_put)
// Inputs: S0, K, T, vt (float32, N each). Output: float32 [N,4].
//
// Round 7: fix compile error — __builtin_nontemporal_store needs a clang
// native vector type, not HIP_vector_type<float,4>. Use ext_vector_type(4).
// Experiment otherwise unchanged: one option per thread (coalesced 4 B loads,
// one coalesced 16 B nt store), fast-math core (validated absmax 0.25 vs
// threshold 0.985), exact-fit one-shot grid (no grid-stride loop).

typedef float f32x4 __attribute__((ext_vector_type(4)));

__global__ void __launch_bounds__(256)
bs_all_kernel(const float* __restrict__ S0, const float* __restrict__ K,
              const float* __restrict__ T, const float* __restrict__ vt,
              f32x4* __restrict__ out, int n) {
    const float LN2 = 0.69314718055994531f;
    const float A   = -2.3048706f;    // -1.5976   * log2(e)
    const float B   = -0.10180522f;   // -0.070566 * log2(e)
    const float CR  = -0.028853901f;  // -0.02 * log2(e)
    const float CQ  = -0.014426951f;  // -0.01 * log2(e)

    int i = blockIdx.x * blockDim.x + threadIdx.x;
    if (i >= n) return;

    float s = S0[i];
    float k = K[i];
    float t = T[i];
    float v = vt[i];

    float x      = v * t;
    float inv_sv = __builtin_amdgcn_rsqf(x);   // 1/sqrt(v*t)
    float sv     = x * inv_sv;                 // sqrt(v*t)

    float lg = (__builtin_amdgcn_logf(s) - __builtin_amdgcn_logf(k)) * LN2;
    float d1 = (lg + fmaf(0.5f, v, 0.01f) * t) * inv_sv;  // R-Q = 0.01
    float d2 = d1 - sv;

    // Phi(d) = 1/(1 + exp2(d*(A + B*d^2)))   (Page 1977 logistic, |err|<=1.4e-4)
    float a1 = d1 * fmaf(B, d1 * d1, A);
    float a2 = d2 * fmaf(B, d2 * d2, A);
    float N1 = __builtin_amdgcn_rcpf(1.0f + __builtin_amdgcn_exp2f(a1));
    float N2 = __builtin_amdgcn_rcpf(1.0f + __builtin_amdgcn_exp2f(a2));

    float disc_r = __builtin_amdgcn_exp2f(CR * t);
    float disc_q = __builtin_amdgcn_exp2f(CQ * t);

    float sq = s * disc_q;
    float kr = k * disc_r;
    float call = fmaf(sq, N1, -kr * N2);
    float put  = call - sq + kr;             // put-call parity (exact algebra)
    float dc   = disc_r * N2;
    float dp   = disc_r - dc;                // disc_r * (1 - N2)

    // expired (t == 0): intrinsic / indicator payoffs (also cleans rsq(0) NaNs)
    bool e = (t == 0.0f);
    call = e ? fmaxf(s - k, 0.0f) : call;
    put  = e ? fmaxf(k - s, 0.0f) : put;
    dc   = e ? ((s > k)  ? 1.0f : 0.0f) : dc;
    dp   = e ? ((s <= k) ? 1.0f : 0.0f) : dp;

    // write-once output: nontemporal so the 131 MB write stream doesn't
    // evict the 134 MB input set from L2/L3
    f32x4 o;
    o.x = call; o.y = put; o.z = dc; o.w = dp;
    __builtin_nontemporal_store(o, &out[i]);
}

extern "C" void kernel_launch(void* const* d_in, const int* in_sizes, int n_in,
                              void* d_out, int out_size, void* d_ws, size_t ws_size,
                              hipStream_t stream) {
    const float* S0 = (const float*)d_in[0];
    const float* K  = (const float*)d_in[1];
    const float* T  = (const float*)d_in[2];
    const float* vt = (const float*)d_in[3];
    float* out = (float*)d_out;
    int n = in_sizes[0];

    int block = 256;
    int grid = (n + block - 1) / block;   // exact fit: 32768 blocks for N=8.4M
    bs_all_kernel<<<grid, block, 0, stream>>>(S0, K, T, vt, (f32x4*)out, n);
}